// Round 1
// baseline (713.333 us; speedup 1.0000x reference)
//
#include <hip/hip_runtime.h>
#include <cstdint>
#include <cstddef>

typedef short  bf16x8 __attribute__((ext_vector_type(8)));
typedef short  s16x4  __attribute__((ext_vector_type(4)));
typedef float  f32x4  __attribute__((ext_vector_type(4)));

#define NEGV (-1e30f)
#define LDT 40   // padded LDS row length (bf16 elems) = 80B: 16B-aligned, conflict-light

__device__ __forceinline__ short f2bf(float x){
    union { float f; unsigned u; } v; v.f = x;
    return (short)((v.u + 0x7fffu + ((v.u >> 16) & 1u)) >> 16);
}
__device__ __forceinline__ float bf2f(short h){
    union { float f; unsigned u; } v; v.u = ((unsigned)(unsigned short)h) << 16; return v.f;
}

// ---------------- prep: W1,W2 -> transposed bf16 hi/lo ----------------
__global__ __launch_bounds__(256)
void k_prep_w(const float* __restrict__ W1, const float* __restrict__ W2,
              short* __restrict__ W1Th, short* __restrict__ W1Tl,
              short* __restrict__ W2Th, short* __restrict__ W2Tl)
{
    int idx = blockIdx.x * 256 + threadIdx.x;      // 0 .. 2*512*512-1
    int w = idx >> 18;
    int e = idx & ((1 << 18) - 1);
    int n = e & 511, k = e >> 9;                   // read W coalesced
    const float* W = w ? W2 : W1;
    float x = W[k * 512 + n];
    short hi = f2bf(x);
    short lo = f2bf(x - bf2f(hi));
    size_t o = (size_t)n * 512 + k;                // WT[n][k]
    if (w) { W2Th[o] = hi; W2Tl[o] = lo; } else { W1Th[o] = hi; W1Tl[o] = lo; }
}

// ---------------- row dots: s0 = c@c_weight, s1 = q@q_weight ----------------
__global__ __launch_bounds__(256)
void k_rowdots(const float* __restrict__ c, const float* __restrict__ q,
               const float* __restrict__ cwv, const float* __restrict__ qwv,
               float* __restrict__ s0, float* __restrict__ s1)
{
    int wave = (int)((blockIdx.x * 256 + threadIdx.x) >> 6);
    int lane = threadIdx.x & 63;
    const int NC = 64 * 1024;
    const float* src; const float* wv; float* dst; int row;
    if (wave < NC) { src = c; wv = cwv; dst = s0; row = wave; }
    else { row = wave - NC; if (row >= 64 * 128) return; src = q; wv = qwv; dst = s1; }
    const float4* rp = (const float4*)(src + (size_t)row * 512);
    const float4* wp = (const float4*)wv;
    float acc = 0.f;
    #pragma unroll
    for (int i = 0; i < 2; i++) {
        float4 a = rp[lane + 64 * i];
        float4 w = wp[lane + 64 * i];
        acc += a.x * w.x + a.y * w.y + a.z * w.z + a.w * w.w;
    }
    #pragma unroll
    for (int off = 32; off; off >>= 1) acc += __shfl_down(acc, off);
    if (lane == 0) dst[row] = acc;
}

// ---------------- split-bf16 linear: Y = relu(X @ W + bias), W pre-transposed ----------------
__global__ __launch_bounds__(256)
void k_linear(const float* __restrict__ X, const short* __restrict__ WTh,
              const short* __restrict__ WTl, const float* __restrict__ bias,
              float* __restrict__ Y)
{
    __shared__ short Ah[128 * LDT], Al[128 * LDT], Bh[128 * LDT], Bl[128 * LDT];
    const int t = threadIdx.x;
    const int m0 = (int)(blockIdx.x >> 2) * 128;
    const int n0 = (int)(blockIdx.x & 3) * 128;
    const int lane = t & 63;
    const int wr = (t >> 7) & 1, wc = (t >> 6) & 1;
    const int fr = lane & 15, fg = lane >> 4;
    const int srow = t >> 1, sk = (t & 1) * 16;

    f32x4 acc[4][4] = {};

    for (int k0 = 0; k0 < 512; k0 += 32) {
        __syncthreads();
        {   // A: fp32 -> hi/lo
            const float* src = X + (size_t)(m0 + srow) * 512 + k0 + sk;
            float4 f[4];
            #pragma unroll
            for (int i = 0; i < 4; i++) f[i] = ((const float4*)src)[i];
            const float* fv = (const float*)f;
            short hi[16], lo[16];
            #pragma unroll
            for (int j = 0; j < 16; j++) {
                float x = fv[j];
                short h = f2bf(x);
                hi[j] = h; lo[j] = f2bf(x - bf2f(h));
            }
            #pragma unroll
            for (int j = 0; j < 2; j++) {
                *(bf16x8*)&Ah[srow * LDT + sk + j * 8] = *(bf16x8*)&hi[j * 8];
                *(bf16x8*)&Al[srow * LDT + sk + j * 8] = *(bf16x8*)&lo[j * 8];
            }
        }
        {   // B: pre-converted bf16 rows of WT
            const short* sh = WTh + (size_t)(n0 + srow) * 512 + k0 + sk;
            const short* sl = WTl + (size_t)(n0 + srow) * 512 + k0 + sk;
            #pragma unroll
            for (int j = 0; j < 2; j++) {
                *(bf16x8*)&Bh[srow * LDT + sk + j * 8] = ((const bf16x8*)sh)[j];
                *(bf16x8*)&Bl[srow * LDT + sk + j * 8] = ((const bf16x8*)sl)[j];
            }
        }
        __syncthreads();
        bf16x8 a_h[4], a_l[4], b_h[4], b_l[4];
        #pragma unroll
        for (int i = 0; i < 4; i++) {
            int ar = (wr * 64 + i * 16 + fr) * LDT + fg * 8;
            int br = (wc * 64 + i * 16 + fr) * LDT + fg * 8;
            a_h[i] = *(const bf16x8*)&Ah[ar];
            a_l[i] = *(const bf16x8*)&Al[ar];
            b_h[i] = *(const bf16x8*)&Bh[br];
            b_l[i] = *(const bf16x8*)&Bl[br];
        }
        #pragma unroll
        for (int mi = 0; mi < 4; mi++)
        #pragma unroll
        for (int ni = 0; ni < 4; ni++) {
            acc[mi][ni] = __builtin_amdgcn_mfma_f32_16x16x32_bf16(a_h[mi], b_h[ni], acc[mi][ni], 0, 0, 0);
            acc[mi][ni] = __builtin_amdgcn_mfma_f32_16x16x32_bf16(a_h[mi], b_l[ni], acc[mi][ni], 0, 0, 0);
            acc[mi][ni] = __builtin_amdgcn_mfma_f32_16x16x32_bf16(a_l[mi], b_h[ni], acc[mi][ni], 0, 0, 0);
        }
    }
    float bv[4];
    #pragma unroll
    for (int ni = 0; ni < 4; ni++) bv[ni] = bias[n0 + wc * 64 + ni * 16 + fr];
    #pragma unroll
    for (int mi = 0; mi < 4; mi++)
    #pragma unroll
    for (int r = 0; r < 4; r++) {
        int row = m0 + wr * 64 + mi * 16 + fg * 4 + r;
        #pragma unroll
        for (int ni = 0; ni < 4; ni++) {
            float v = acc[mi][ni][r] + bv[ni];
            Y[(size_t)row * 512 + n0 + wc * 64 + ni * 16 + fr] = fmaxf(v, 0.f);
        }
    }
}

// ---------------- attention logits GEMM (NT): Sout[b] = A[b] @ B[b]^T (+ s0 + s1 + bias) ----------------
template<bool SPLIT, bool AMUL, bool ADDS>
__global__ __launch_bounds__(256)
void k_att_gemm(const float* __restrict__ Cc, const float* __restrict__ Qq,
                const float* __restrict__ cqw, const float* __restrict__ s0v,
                const float* __restrict__ s1v, const float* __restrict__ biasp,
                float* __restrict__ Sout)
{
    __shared__ short Ah[128 * LDT], Bh[128 * LDT];
    __shared__ short Al[SPLIT ? 128 * LDT : 8], Bl[SPLIT ? 128 * LDT : 8];
    __shared__ float cqs[AMUL ? 512 : 8];

    const int t = threadIdx.x;
    const int b  = (int)(blockIdx.x >> 3);
    const int m0 = (int)(blockIdx.x & 7) * 128;
    const int lane = t & 63;
    const int wr = (t >> 7) & 1, wc = (t >> 6) & 1;
    const int fr = lane & 15, fg = lane >> 4;
    const int srow = t >> 1, sk = (t & 1) * 16;

    if (AMUL) { cqs[t] = cqw[t]; cqs[t + 256] = cqw[t + 256]; }

    f32x4 acc[4][4] = {};

    for (int k0 = 0; k0 < 512; k0 += 32) {
        __syncthreads();
        {   // A from c (optionally * cq_weight), split if requested
            const float* src = Cc + ((size_t)b * 1024 + m0 + srow) * 512 + k0 + sk;
            float4 f[4];
            #pragma unroll
            for (int i = 0; i < 4; i++) f[i] = ((const float4*)src)[i];
            const float* fv = (const float*)f;
            short hi[16], lo[16];
            #pragma unroll
            for (int j = 0; j < 16; j++) {
                float x = fv[j];
                if (AMUL) x *= cqs[k0 + sk + j];
                short h = f2bf(x);
                hi[j] = h;
                if (SPLIT) lo[j] = f2bf(x - bf2f(h));
            }
            #pragma unroll
            for (int j = 0; j < 2; j++) {
                *(bf16x8*)&Ah[srow * LDT + sk + j * 8] = *(bf16x8*)&hi[j * 8];
                if (SPLIT) *(bf16x8*)&Al[srow * LDT + sk + j * 8] = *(bf16x8*)&lo[j * 8];
            }
        }
        {   // B from Qq rows (q or qp), split if requested
            const float* src = Qq + ((size_t)b * 128 + srow) * 512 + k0 + sk;
            float4 f[4];
            #pragma unroll
            for (int i = 0; i < 4; i++) f[i] = ((const float4*)src)[i];
            const float* fv = (const float*)f;
            short hi[16], lo[16];
            #pragma unroll
            for (int j = 0; j < 16; j++) {
                float x = fv[j];
                short h = f2bf(x);
                hi[j] = h;
                if (SPLIT) lo[j] = f2bf(x - bf2f(h));
            }
            #pragma unroll
            for (int j = 0; j < 2; j++) {
                *(bf16x8*)&Bh[srow * LDT + sk + j * 8] = *(bf16x8*)&hi[j * 8];
                if (SPLIT) *(bf16x8*)&Bl[srow * LDT + sk + j * 8] = *(bf16x8*)&lo[j * 8];
            }
        }
        __syncthreads();
        bf16x8 a_h[4], b_h[4];
        bf16x8 a_l[4], b_l[4];
        #pragma unroll
        for (int i = 0; i < 4; i++) {
            int ar = (wr * 64 + i * 16 + fr) * LDT + fg * 8;
            int br = (wc * 64 + i * 16 + fr) * LDT + fg * 8;
            a_h[i] = *(const bf16x8*)&Ah[ar];
            b_h[i] = *(const bf16x8*)&Bh[br];
            if (SPLIT) { a_l[i] = *(const bf16x8*)&Al[ar]; b_l[i] = *(const bf16x8*)&Bl[br]; }
        }
        #pragma unroll
        for (int mi = 0; mi < 4; mi++)
        #pragma unroll
        for (int ni = 0; ni < 4; ni++) {
            acc[mi][ni] = __builtin_amdgcn_mfma_f32_16x16x32_bf16(a_h[mi], b_h[ni], acc[mi][ni], 0, 0, 0);
            if (SPLIT) {
                acc[mi][ni] = __builtin_amdgcn_mfma_f32_16x16x32_bf16(a_h[mi], b_l[ni], acc[mi][ni], 0, 0, 0);
                acc[mi][ni] = __builtin_amdgcn_mfma_f32_16x16x32_bf16(a_l[mi], b_h[ni], acc[mi][ni], 0, 0, 0);
            }
        }
    }
    float b0 = 0.f;
    float s1c[4];
    if (ADDS) {
        b0 = biasp[0];
        #pragma unroll
        for (int ni = 0; ni < 4; ni++) s1c[ni] = s1v[b * 128 + wc * 64 + ni * 16 + fr];
    }
    #pragma unroll
    for (int mi = 0; mi < 4; mi++)
    #pragma unroll
    for (int r = 0; r < 4; r++) {
        int row = m0 + wr * 64 + mi * 16 + fg * 4 + r;
        float s0r = ADDS ? (s0v[b * 1024 + row] + b0) : 0.f;
        #pragma unroll
        for (int ni = 0; ni < 4; ni++) {
            int col = wc * 64 + ni * 16 + fr;
            float v = acc[mi][ni][r];
            if (ADDS) v += s0r + s1c[ni];
            Sout[((size_t)b * 1024 + row) * 128 + col] = v;
        }
    }
}

// ---------------- dual softmax stats over one 128-row chunk ----------------
__global__ __launch_bounds__(512)
void k_stats(const float* __restrict__ S, const int* __restrict__ qmask,
             const int* __restrict__ cmask, float2* __restrict__ rowst,
             float2* __restrict__ colpart)
{
    __shared__ float redA[8], redB[8];
    __shared__ float2 colred[4][128];
    __shared__ int cms[128];
    const int t = threadIdx.x;
    const int b = (int)(blockIdx.x >> 3), ch = (int)(blockIdx.x & 7);
    const int r0 = ch * 128;
    const int q = t & 127, ig = t >> 7;
    if (t < 128) cms[t] = cmask[b * 1024 + r0 + t];
    const bool qm = qmask[b * 128 + q] != 0;
    float vals[32];
    const float* base = S + ((size_t)b * 1024 + r0 + ig * 32) * 128 + q;
    #pragma unroll
    for (int i = 0; i < 32; i++) vals[i] = base[(size_t)i * 128];
    __syncthreads();
    const int wv = t >> 6;
    // row stats (each (ig,i) pair of waves owns one full row of 128)
    #pragma unroll
    for (int i = 0; i < 32; i++) {
        float v = vals[i];
        float m = qm ? v : NEGV;
        #pragma unroll
        for (int off = 32; off; off >>= 1) m = fmaxf(m, __shfl_xor(m, off));
        if ((t & 63) == 0) redA[wv] = m;
        __syncthreads();
        m = fmaxf(redA[ig * 2], redA[ig * 2 + 1]);
        float e = qm ? __expf(v - m) : 0.f;
        #pragma unroll
        for (int off = 32; off; off >>= 1) e += __shfl_xor(e, off);
        if ((t & 63) == 0) redB[wv] = e;
        __syncthreads();
        if (q == 0) {
            float sum = redB[ig * 2] + redB[ig * 2 + 1];
            rowst[(size_t)b * 1024 + r0 + ig * 32 + i] = make_float2(m, sum);
        }
    }
    // column partials (per q over this chunk's 128 rows)
    float cmax = NEGV;
    #pragma unroll
    for (int i = 0; i < 32; i++) if (cms[ig * 32 + i]) cmax = fmaxf(cmax, vals[i]);
    float csum = 0.f;
    #pragma unroll
    for (int i = 0; i < 32; i++) if (cms[ig * 32 + i]) csum += __expf(vals[i] - cmax);
    colred[ig][q] = make_float2(cmax, csum);
    __syncthreads();
    if (t < 128) {
        float M = NEGV;
        #pragma unroll
        for (int g = 0; g < 4; g++) M = fmaxf(M, colred[g][t].x);
        float Ss = 0.f;
        #pragma unroll
        for (int g = 0; g < 4; g++) {
            float2 p = colred[g][t];
            Ss += p.y * __expf(p.x - M);
        }
        colpart[((size_t)b * 8 + ch) * 128 + t] = make_float2(M, Ss);
    }
}

// ---------------- combine 8 column partials ----------------
__global__ __launch_bounds__(256)
void k_colfin(const float2* __restrict__ colpart, float2* __restrict__ colfin)
{
    int idx = blockIdx.x * 256 + threadIdx.x;    // 8192 = B * 128
    int b = idx >> 7, qq = idx & 127;
    float M = NEGV;
    #pragma unroll
    for (int ch = 0; ch < 8; ch++) M = fmaxf(M, colpart[((size_t)b * 8 + ch) * 128 + qq].x);
    float S = 0.f;
    #pragma unroll
    for (int ch = 0; ch < 8; ch++) {
        float2 p = colpart[((size_t)b * 8 + ch) * 128 + qq];
        S += p.y * __expf(p.x - M);
    }
    colfin[idx] = make_float2(M, S);
}

// ---------------- emit normalized softmaxes: Pr (row, [B,1024,128]) and PcT (col, transposed [B,128,1024]) ----------------
__global__ __launch_bounds__(512)
void k_emit(const float* __restrict__ S, const int* __restrict__ qmask,
            const int* __restrict__ cmask, const float2* __restrict__ rowst,
            const float2* __restrict__ colfin, short* __restrict__ Pr,
            short* __restrict__ PcT)
{
    const int t = threadIdx.x;
    const int b = (int)(blockIdx.x >> 3), ch = (int)(blockIdx.x & 7);
    const int r0 = ch * 128;
    {   // row softmax, linear layout
        const int q = t & 127, rg = t >> 7;
        const bool qm = qmask[b * 128 + q] != 0;
        #pragma unroll 8
        for (int i = 0; i < 32; i++) {
            int r = r0 + rg * 32 + i;
            size_t idx = ((size_t)b * 1024 + r) * 128 + q;
            float v = S[idx];
            float2 rs = rowst[(size_t)b * 1024 + r];
            float o = qm ? __expf(v - rs.x) / rs.y : 0.f;
            Pr[idx] = f2bf(o);
        }
    }
    {   // column softmax, transposed layout
        const int q2 = t >> 2, ig = t & 3;
        float2 cs = colfin[b * 128 + q2];
        float inv = 1.f / cs.y;
        short buf[32];
        #pragma unroll
        for (int i = 0; i < 32; i++) {
            int r = r0 + ig * 32 + i;
            bool cm = cmask[b * 1024 + r] != 0;
            float v = S[((size_t)b * 1024 + r) * 128 + q2];
            buf[i] = f2bf(cm ? __expf(v - cs.x) * inv : 0.f);
        }
        short* dst = PcT + ((size_t)b * 128 + q2) * 1024 + r0 + ig * 32;
        #pragma unroll
        for (int j = 0; j < 4; j++) *(bf16x8*)(dst + j * 8) = *(bf16x8*)&buf[j * 8];
    }
}

// ---------------- K=1024 GEMM: Y[b] = A[b] (bf16 [128,1024]) @ c[b] ([1024,512] fp32, transpose-staged) -> bf16 ----------------
__global__ __launch_bounds__(256)
void k_kgemm(const short* __restrict__ A, const float* __restrict__ Cc,
             short* __restrict__ Y)
{
    __shared__ short As[128 * LDT], Bs[128 * LDT];
    const int t = threadIdx.x;
    const int b = (int)(blockIdx.x >> 2);
    const int n0 = (int)(blockIdx.x & 3) * 128;
    const int lane = t & 63;
    const int wr = (t >> 7) & 1, wc = (t >> 6) & 1;
    const int fr = lane & 15, fg = lane >> 4;
    const int srow = t >> 1, sk = (t & 1) * 16;
    const int n4 = (t & 31) * 4, kk4 = (t >> 5) * 4;
    f32x4 acc[4][4] = {};
    for (int k0 = 0; k0 < 1024; k0 += 32) {
        __syncthreads();
        {
            const short* as = A + ((size_t)b * 128 + srow) * 1024 + k0 + sk;
            *(bf16x8*)&As[srow * LDT + sk]     = ((const bf16x8*)as)[0];
            *(bf16x8*)&As[srow * LDT + sk + 8] = ((const bf16x8*)as)[1];
        }
        {
            const float* bsrc = Cc + ((size_t)b * 1024 + k0 + kk4) * 512 + n0 + n4;
            float4 r0_ = *(const float4*)(bsrc);
            float4 r1_ = *(const float4*)(bsrc + 512);
            float4 r2_ = *(const float4*)(bsrc + 1024);
            float4 r3_ = *(const float4*)(bsrc + 1536);
            const float* p0 = (const float*)&r0_;
            const float* p1 = (const float*)&r1_;
            const float* p2 = (const float*)&r2_;
            const float* p3 = (const float*)&r3_;
            #pragma unroll
            for (int l = 0; l < 4; l++) {
                unsigned d0 = (unsigned)(unsigned short)f2bf(p0[l]) | ((unsigned)(unsigned short)f2bf(p1[l]) << 16);
                unsigned d1 = (unsigned)(unsigned short)f2bf(p2[l]) | ((unsigned)(unsigned short)f2bf(p3[l]) << 16);
                uint2 dd; dd.x = d0; dd.y = d1;
                *(uint2*)&Bs[(n4 + l) * LDT + kk4] = dd;
            }
        }
        __syncthreads();
        bf16x8 af[4], bg[4];
        #pragma unroll
        for (int i = 0; i < 4; i++) {
            af[i] = *(const bf16x8*)&As[(wr * 64 + i * 16 + fr) * LDT + fg * 8];
            bg[i] = *(const bf16x8*)&Bs[(wc * 64 + i * 16 + fr) * LDT + fg * 8];
        }
        #pragma unroll
        for (int mi = 0; mi < 4; mi++)
        #pragma unroll
        for (int ni = 0; ni < 4; ni++)
            acc[mi][ni] = __builtin_amdgcn_mfma_f32_16x16x32_bf16(af[mi], bg[ni], acc[mi][ni], 0, 0, 0);
    }
    #pragma unroll
    for (int mi = 0; mi < 4; mi++)
    #pragma unroll
    for (int r = 0; r < 4; r++) {
        int row = wr * 64 + mi * 16 + fg * 4 + r;
        #pragma unroll
        for (int ni = 0; ni < 4; ni++)
            Y[((size_t)b * 128 + row) * 512 + n0 + wc * 64 + ni * 16 + fr] = f2bf(acc[mi][ni][r]);
    }
}

// ---------------- epilogue GEMM (K=128), fused final output writes ----------------
template<bool WITHC>
__global__ __launch_bounds__(256)
void k_epi(const short* __restrict__ Sm, const float* __restrict__ B1f,
           const short* __restrict__ B2b, const float* __restrict__ Cc,
           float* __restrict__ out)
{
    __shared__ short As[128 * LDT], B1s[128 * LDT], B2s[128 * LDT];
    const int t = threadIdx.x;
    const int hb = (int)(blockIdx.x & 3);
    const int mb = (int)((blockIdx.x >> 2) & 7);
    const int b  = (int)(blockIdx.x >> 5);
    const int m0 = mb * 128, h0 = hb * 128;
    const int lane = t & 63;
    const int wr = (t >> 7) & 1, wc = (t >> 6) & 1;
    const int fr = lane & 15, fg = lane >> 4;
    const int srow = t >> 1, sk = (t & 1) * 16;
    const int n4 = (t & 31) * 4, kk4 = (t >> 5) * 4;
    f32x4 acc1[4][4] = {}, acc2[4][4] = {};
    for (int k0 = 0; k0 < 128; k0 += 32) {
        __syncthreads();
        {
            const short* as = Sm + ((size_t)b * 1024 + m0 + srow) * 128 + k0 + sk;
            *(bf16x8*)&As[srow * LDT + sk]     = ((const bf16x8*)as)[0];
            *(bf16x8*)&As[srow * LDT + sk + 8] = ((const bf16x8*)as)[1];
        }
        {   // B1: fp32 [128,512], transpose-stage
            const float* bsrc = B1f + ((size_t)b * 128 + k0 + kk4) * 512 + h0 + n4;
            float4 r0_ = *(const float4*)(bsrc);
            float4 r1_ = *(const float4*)(bsrc + 512);
            float4 r2_ = *(const float4*)(bsrc + 1024);
            float4 r3_ = *(const float4*)(bsrc + 1536);
            const float* p0 = (const float*)&r0_;
            const float* p1 = (const float*)&r1_;
            const float* p2 = (const float*)&r2_;
            const float* p3 = (const float*)&r3_;
            #pragma unroll
            for (int l = 0; l < 4; l++) {
                unsigned d0 = (unsigned)(unsigned short)f2bf(p0[l]) | ((unsigned)(unsigned short)f2bf(p1[l]) << 16);
                unsigned d1 = (unsigned)(unsigned short)f2bf(p2[l]) | ((unsigned)(unsigned short)f2bf(p3[l]) << 16);
                uint2 dd; dd.x = d0; dd.y = d1;
                *(uint2*)&B1s[(n4 + l) * LDT + kk4] = dd;
            }
        }
        {   // B2: bf16 [128,512], transpose-stage
            const short* b2 = B2b + ((size_t)b * 128 + k0 + kk4) * 512 + h0 + n4;
            s16x4 u0 = *(const s16x4*)(b2);
            s16x4 u1 = *(const s16x4*)(b2 + 512);
            s16x4 u2 = *(const s16x4*)(b2 + 1024);
            s16x4 u3 = *(const s16x4*)(b2 + 1536);
            #pragma unroll
            for (int l = 0; l < 4; l++) {
                unsigned d0 = (unsigned)(unsigned short)u0[l] | ((unsigned)(unsigned short)u1[l] << 16);
                unsigned d1 = (unsigned)(unsigned short)u2[l] | ((unsigned)(unsigned short)u3[l] << 16);
                uint2 dd; dd.x = d0; dd.y = d1;
                *(uint2*)&B2s[(n4 + l) * LDT + kk4] = dd;
            }
        }
        __syncthreads();
        bf16x8 af[4], b1g[4], b2g[4];
        #pragma unroll
        for (int i = 0; i < 4; i++) {
            af[i]  = *(const bf16x8*)&As[(wr * 64 + i * 16 + fr) * LDT + fg * 8];
            b1g[i] = *(const bf16x8*)&B1s[(wc * 64 + i * 16 + fr) * LDT + fg * 8];
            b2g[i] = *(const bf16x8*)&B2s[(wc * 64 + i * 16 + fr) * LDT + fg * 8];
        }
        #pragma unroll
        for (int mi = 0; mi < 4; mi++)
        #pragma unroll
        for (int ni = 0; ni < 4; ni++) {
            acc1[mi][ni] = __builtin_amdgcn_mfma_f32_16x16x32_bf16(af[mi], b1g[ni], acc1[mi][ni], 0, 0, 0);
            acc2[mi][ni] = __builtin_amdgcn_mfma_f32_16x16x32_bf16(af[mi], b2g[ni], acc2[mi][ni], 0, 0, 0);
        }
    }
    const size_t crow_base = (size_t)b * 1024 + m0;
    #pragma unroll
    for (int mi = 0; mi < 4; mi++)
    #pragma unroll
    for (int r = 0; r < 4; r++) {
        int rowl = wr * 64 + mi * 16 + fg * 4 + r;
        size_t obase = (crow_base + rowl) * 3072 + h0;
        #pragma unroll
        for (int ni = 0; ni < 4; ni++) {
            int col = wc * 64 + ni * 16 + fr;
            float av = acc1[mi][ni][r], bv2 = acc2[mi][ni][r];
            if (WITHC) {
                float cv = Cc[(crow_base + rowl) * 512 + h0 + col];
                out[obase + col]        = cv;
                out[obase + col + 512]  = av;
                out[obase + col + 1024] = cv * av;
                out[obase + col + 1536] = cv * bv2;
            } else {
                out[obase + col + 2048] = bv2;
                out[obase + col + 2560] = av;
            }
        }
    }
}

// ---------------- host launcher ----------------
extern "C" void kernel_launch(void* const* d_in, const int* in_sizes, int n_in,
                              void* d_out, int out_size, void* d_ws, size_t ws_size,
                              hipStream_t stream)
{
    const float* c     = (const float*)d_in[0];
    const float* q     = (const float*)d_in[1];
    const int*   cmask = (const int*)d_in[2];
    const int*   qmask = (const int*)d_in[3];
    const float* cwv   = (const float*)d_in[4];
    const float* qwv   = (const float*)d_in[5];
    const float* cqw   = (const float*)d_in[6];
    const float* bias  = (const float*)d_in[7];
    const float* W1    = (const float*)d_in[8];
    const float* b1    = (const float*)d_in[9];
    const float* W2    = (const float*)d_in[10];
    const float* b2    = (const float*)d_in[11];
    float* out = (float*)d_out;

    char* ws = (char*)d_ws;
    size_t off = 0;
    auto alloc = [&](size_t bytes) -> char* {
        char* p = ws + off;
        off = (off + bytes + 255) & ~(size_t)255;
        return p;
    };
    short* w1th = (short*)alloc(512 * 512 * 2);
    short* w1tl = (short*)alloc(512 * 512 * 2);
    short* w2th = (short*)alloc(512 * 512 * 2);
    short* w2tl = (short*)alloc(512 * 512 * 2);
    float* s0   = (float*)alloc(64 * 1024 * 4);
    float* s1   = (float*)alloc(64 * 128 * 4);
    float* z1   = (float*)alloc((size_t)8192 * 512 * 4);   // later reused for binner+bcoat
    float* qp   = (float*)alloc((size_t)8192 * 512 * 4);
    float* simb = (float*)alloc((size_t)64 * 1024 * 128 * 4); // shared by sim & scoat
    float2* rowst   = (float2*)alloc((size_t)64 * 1024 * 8);
    float2* colpart = (float2*)alloc((size_t)64 * 8 * 128 * 8);
    float2* colfin  = (float2*)alloc((size_t)64 * 128 * 8);
    short* s1s  = (short*)alloc((size_t)64 * 1024 * 128 * 2);
    short* s2sT = (short*)alloc((size_t)64 * 128 * 1024 * 2);
    short* sc1  = (short*)alloc((size_t)64 * 1024 * 128 * 2);
    short* sc2T = (short*)alloc((size_t)64 * 128 * 1024 * 2);
    short* binner = (short*)z1;
    short* bcoat  = ((short*)z1) + (size_t)64 * 128 * 512;

    k_prep_w<<<2048, 256, 0, stream>>>(W1, W2, w1th, w1tl, w2th, w2tl);
    k_rowdots<<<18432, 256, 0, stream>>>(c, q, cwv, qwv, s0, s1);
    k_linear<<<256, 256, 0, stream>>>(q, w1th, w1tl, b1, z1);
    k_linear<<<256, 256, 0, stream>>>(z1, w2th, w2tl, b2, qp);

    // sim pipeline
    k_att_gemm<false, true, true><<<512, 256, 0, stream>>>(c, q, cqw, s0, s1, bias, simb);
    k_stats<<<512, 512, 0, stream>>>(simb, qmask, cmask, rowst, colpart);
    k_colfin<<<32, 256, 0, stream>>>(colpart, colfin);
    k_emit<<<512, 512, 0, stream>>>(simb, qmask, cmask, rowst, colfin, s1s, s2sT);

    // scoat pipeline (split precision: unscaled logits feed a sharp softmax)
    k_att_gemm<true, false, false><<<512, 256, 0, stream>>>(c, qp, nullptr, nullptr, nullptr, nullptr, simb);
    k_stats<<<512, 512, 0, stream>>>(simb, qmask, cmask, rowst, colpart);
    k_colfin<<<32, 256, 0, stream>>>(colpart, colfin);
    k_emit<<<512, 512, 0, stream>>>(simb, qmask, cmask, rowst, colfin, sc1, sc2T);

    // K=1024 column-attention GEMMs
    k_kgemm<<<256, 256, 0, stream>>>(s2sT, c, binner);
    k_kgemm<<<256, 256, 0, stream>>>(sc2T, c, bcoat);

    // fused output epilogues
    k_epi<true><<<2048, 256, 0, stream>>>(s1s, q, binner, c, out);
    k_epi<false><<<2048, 256, 0, stream>>>(sc1, qp, bcoat, c, out);
}

// Round 2
// 690.660 us; speedup vs baseline: 1.0328x; 1.0328x over previous
//
#include <hip/hip_runtime.h>
#include <cstdint>
#include <cstddef>

typedef short  bf16x8 __attribute__((ext_vector_type(8)));
typedef float  f32x4  __attribute__((ext_vector_type(4)));

#define NEGV (-1e30f)
#define LDT 40   // padded LDS row length (bf16 elems)

__device__ __forceinline__ short f2bf(float x){
    union { float f; unsigned u; } v; v.f = x;
    return (short)((v.u + 0x7fffu + ((v.u >> 16) & 1u)) >> 16);
}
__device__ __forceinline__ float bf2f(short h){
    union { float f; unsigned u; } v; v.u = ((unsigned)(unsigned short)h) << 16; return v.f;
}

// ---------------- prep: W1,W2 -> transposed bf16 hi/lo ----------------
__global__ __launch_bounds__(256)
void k_prep_w(const float* __restrict__ W1, const float* __restrict__ W2,
              short* __restrict__ W1Th, short* __restrict__ W1Tl,
              short* __restrict__ W2Th, short* __restrict__ W2Tl)
{
    int idx = blockIdx.x * 256 + threadIdx.x;
    int w = idx >> 18;
    int e = idx & ((1 << 18) - 1);
    int n = e & 511, k = e >> 9;
    const float* W = w ? W2 : W1;
    float x = W[k * 512 + n];
    short hi = f2bf(x);
    short lo = f2bf(x - bf2f(hi));
    size_t o = (size_t)n * 512 + k;
    if (w) { W2Th[o] = hi; W2Tl[o] = lo; } else { W1Th[o] = hi; W1Tl[o] = lo; }
}

// ---------------- q -> qT bf16 [B,512,128] ----------------
__global__ __launch_bounds__(256)
void k_transq(const float* __restrict__ q, short* __restrict__ qT)
{
    __shared__ short TT[128 * 136];
    const int t = threadIdx.x;
    const int b = (int)(blockIdx.x >> 2), h0 = (int)(blockIdx.x & 3) * 128;
    #pragma unroll
    for (int it = 0; it < 16; it++) {
        int idx = it * 256 + t;
        int m = idx >> 5, c4 = (idx & 31) * 4;
        float4 v = *(const float4*)(q + ((size_t)b * 128 + m) * 512 + h0 + c4);
        TT[(c4 + 0) * 136 + m] = f2bf(v.x);
        TT[(c4 + 1) * 136 + m] = f2bf(v.y);
        TT[(c4 + 2) * 136 + m] = f2bf(v.z);
        TT[(c4 + 3) * 136 + m] = f2bf(v.w);
    }
    __syncthreads();
    const int h = t >> 1, half = t & 1;
    short* dst = qT + ((size_t)b * 512 + h0 + h) * 128 + half * 64;
    #pragma unroll
    for (int j = 0; j < 8; j++)
        *(bf16x8*)(dst + j * 8) = *(const bf16x8*)&TT[h * 136 + half * 64 + j * 8];
}

// ---------------- split-bf16 linear: Y = relu(X@W + bias); optional transposed bf16 copy ----------------
template<bool WT>
__global__ __launch_bounds__(256)
void k_linear(const float* __restrict__ X, const short* __restrict__ WTh,
              const short* __restrict__ WTl, const float* __restrict__ bias,
              float* __restrict__ Y, short* __restrict__ YT)
{
    __shared__ short SMEM[4 * 128 * LDT];
    short* Ah = SMEM;
    short* Al = SMEM + 128 * LDT;
    short* Bh = SMEM + 2 * 128 * LDT;
    short* Bl = SMEM + 3 * 128 * LDT;
    const int t = threadIdx.x;
    const int m0 = (int)(blockIdx.x >> 2) * 128;
    const int n0 = (int)(blockIdx.x & 3) * 128;
    const int lane = t & 63;
    const int wr = (t >> 7) & 1, wc = (t >> 6) & 1;
    const int fr = lane & 15, fg = lane >> 4;
    const int srow = t >> 1, sk = (t & 1) * 16;

    f32x4 acc[4][4] = {};

    for (int k0 = 0; k0 < 512; k0 += 32) {
        __syncthreads();
        {
            const float* src = X + (size_t)(m0 + srow) * 512 + k0 + sk;
            float4 f[4];
            #pragma unroll
            for (int i = 0; i < 4; i++) f[i] = ((const float4*)src)[i];
            const float* fv = (const float*)f;
            short hi[16], lo[16];
            #pragma unroll
            for (int j = 0; j < 16; j++) {
                float x = fv[j];
                short h = f2bf(x);
                hi[j] = h; lo[j] = f2bf(x - bf2f(h));
            }
            #pragma unroll
            for (int j = 0; j < 2; j++) {
                *(bf16x8*)&Ah[srow * LDT + sk + j * 8] = *(bf16x8*)&hi[j * 8];
                *(bf16x8*)&Al[srow * LDT + sk + j * 8] = *(bf16x8*)&lo[j * 8];
            }
        }
        {
            const short* sh = WTh + (size_t)(n0 + srow) * 512 + k0 + sk;
            const short* sl = WTl + (size_t)(n0 + srow) * 512 + k0 + sk;
            #pragma unroll
            for (int j = 0; j < 2; j++) {
                *(bf16x8*)&Bh[srow * LDT + sk + j * 8] = ((const bf16x8*)sh)[j];
                *(bf16x8*)&Bl[srow * LDT + sk + j * 8] = ((const bf16x8*)sl)[j];
            }
        }
        __syncthreads();
        bf16x8 a_h[4], a_l[4], b_h[4], b_l[4];
        #pragma unroll
        for (int i = 0; i < 4; i++) {
            int ar = (wr * 64 + i * 16 + fr) * LDT + fg * 8;
            int br = (wc * 64 + i * 16 + fr) * LDT + fg * 8;
            a_h[i] = *(const bf16x8*)&Ah[ar];
            a_l[i] = *(const bf16x8*)&Al[ar];
            b_h[i] = *(const bf16x8*)&Bh[br];
            b_l[i] = *(const bf16x8*)&Bl[br];
        }
        #pragma unroll
        for (int mi = 0; mi < 4; mi++)
        #pragma unroll
        for (int ni = 0; ni < 4; ni++) {
            acc[mi][ni] = __builtin_amdgcn_mfma_f32_16x16x32_bf16(a_h[mi], b_h[ni], acc[mi][ni], 0, 0, 0);
            acc[mi][ni] = __builtin_amdgcn_mfma_f32_16x16x32_bf16(a_h[mi], b_l[ni], acc[mi][ni], 0, 0, 0);
            acc[mi][ni] = __builtin_amdgcn_mfma_f32_16x16x32_bf16(a_l[mi], b_h[ni], acc[mi][ni], 0, 0, 0);
        }
    }
    float bv[4];
    #pragma unroll
    for (int ni = 0; ni < 4; ni++) bv[ni] = bias[n0 + wc * 64 + ni * 16 + fr];
    #pragma unroll
    for (int mi = 0; mi < 4; mi++)
    #pragma unroll
    for (int r = 0; r < 4; r++) {
        int row = m0 + wr * 64 + mi * 16 + fg * 4 + r;
        #pragma unroll
        for (int ni = 0; ni < 4; ni++) {
            float v = fmaxf(acc[mi][ni][r] + bv[ni], 0.f);
            Y[(size_t)row * 512 + n0 + wc * 64 + ni * 16 + fr] = v;
        }
    }
    if (WT) {
        __syncthreads();
        short* TT = SMEM;   // 40 KB staging space reused (needs 34 KB)
        #pragma unroll
        for (int mi = 0; mi < 4; mi++)
        #pragma unroll
        for (int r = 0; r < 4; r++) {
            int ml = wr * 64 + mi * 16 + fg * 4 + r;
            #pragma unroll
            for (int ni = 0; ni < 4; ni++) {
                int nl = wc * 64 + ni * 16 + fr;
                TT[nl * 136 + ml] = f2bf(fmaxf(acc[mi][ni][r] + bv[ni], 0.f));
            }
        }
        __syncthreads();
        const int n = t >> 1, half = t & 1;
        short* dst = YT + ((size_t)(m0 >> 7) * 512 + n0 + n) * 128 + half * 64;
        #pragma unroll
        for (int j = 0; j < 8; j++)
            *(bf16x8*)(dst + j * 8) = *(const bf16x8*)&TT[n * 136 + half * 64 + j * 8];
    }
}

// ---------------- attention logits GEMM + fused dual-softmax stats ----------------
// Sout[b,row,col] = A[b]@B[b]^T (+ s0 + s1 + bias); also writes rowst (row max/sum
// over masked cols) and colpart (per-128-row-chunk col max/sum over masked rows).
template<bool SPLIT, bool AMUL, bool ADDS>
__global__ __launch_bounds__(256)
void k_att_gemm(const float* __restrict__ Cc, const float* __restrict__ Qq,
                const float* __restrict__ cqw, const float* __restrict__ cwv,
                const float* __restrict__ qwv, const float* __restrict__ biasp,
                const int* __restrict__ qmask, const int* __restrict__ cmask,
                float* __restrict__ Sout, float2* __restrict__ rowst,
                float2* __restrict__ colpart)
{
    __shared__ short Ah[128 * LDT], Bh[128 * LDT];
    __shared__ short Al[SPLIT ? 128 * LDT : 8], Bl[SPLIT ? 128 * LDT : 8];
    __shared__ float cqs[AMUL ? 512 : 8];
    __shared__ float cws[ADDS ? 512 : 8], qws[ADDS ? 512 : 8];
    __shared__ float red[2][128];
    __shared__ float mrowL[128], cmaxL[128];
    __shared__ float s0red[ADDS ? 128 : 1][2], s1red[ADDS ? 128 : 1][2];
    __shared__ float s0arr[ADDS ? 128 : 1], s1arr[ADDS ? 128 : 1];
    __shared__ int qmsL[128], cmsL[128];

    const int t = threadIdx.x;
    const int b  = (int)(blockIdx.x >> 3);
    const int ch = (int)(blockIdx.x & 7);
    const int m0 = ch * 128;
    const int lane = t & 63;
    const int wr = (t >> 7) & 1, wc = (t >> 6) & 1;
    const int fr = lane & 15, fg = lane >> 4;
    const int srow = t >> 1, sk = (t & 1) * 16;

    if (AMUL) { cqs[t] = cqw[t]; cqs[t + 256] = cqw[t + 256]; }
    if (ADDS) {
        cws[t] = cwv[t]; cws[t + 256] = cwv[t + 256];
        qws[t] = qwv[t]; qws[t + 256] = qwv[t + 256];
    }
    if (t < 128) { qmsL[t] = qmask[b * 128 + t]; cmsL[t] = cmask[b * 1024 + m0 + t]; }

    float s0part = 0.f, s1part = 0.f;
    f32x4 acc[4][4] = {};

    for (int k0 = 0; k0 < 512; k0 += 32) {
        __syncthreads();
        {   // A from c
            const float* src = Cc + ((size_t)b * 1024 + m0 + srow) * 512 + k0 + sk;
            float4 f[4];
            #pragma unroll
            for (int i = 0; i < 4; i++) f[i] = ((const float4*)src)[i];
            const float* fv = (const float*)f;
            short hi[16], lo[16];
            #pragma unroll
            for (int j = 0; j < 16; j++) {
                float raw = fv[j];
                if (ADDS) s0part += raw * cws[k0 + sk + j];
                float x = raw;
                if (AMUL) x *= cqs[k0 + sk + j];
                short h = f2bf(x);
                hi[j] = h;
                if (SPLIT) lo[j] = f2bf(x - bf2f(h));
            }
            #pragma unroll
            for (int j = 0; j < 2; j++) {
                *(bf16x8*)&Ah[srow * LDT + sk + j * 8] = *(bf16x8*)&hi[j * 8];
                if (SPLIT) *(bf16x8*)&Al[srow * LDT + sk + j * 8] = *(bf16x8*)&lo[j * 8];
            }
        }
        {   // B from Qq
            const float* src = Qq + ((size_t)b * 128 + srow) * 512 + k0 + sk;
            float4 f[4];
            #pragma unroll
            for (int i = 0; i < 4; i++) f[i] = ((const float4*)src)[i];
            const float* fv = (const float*)f;
            short hi[16], lo[16];
            #pragma unroll
            for (int j = 0; j < 16; j++) {
                float x = fv[j];
                if (ADDS) s1part += x * qws[k0 + sk + j];
                short h = f2bf(x);
                hi[j] = h;
                if (SPLIT) lo[j] = f2bf(x - bf2f(h));
            }
            #pragma unroll
            for (int j = 0; j < 2; j++) {
                *(bf16x8*)&Bh[srow * LDT + sk + j * 8] = *(bf16x8*)&hi[j * 8];
                if (SPLIT) *(bf16x8*)&Bl[srow * LDT + sk + j * 8] = *(bf16x8*)&lo[j * 8];
            }
        }
        __syncthreads();
        bf16x8 a_h[4], b_h[4], a_l[4], b_l[4];
        #pragma unroll
        for (int i = 0; i < 4; i++) {
            int ar = (wr * 64 + i * 16 + fr) * LDT + fg * 8;
            int br = (wc * 64 + i * 16 + fr) * LDT + fg * 8;
            a_h[i] = *(const bf16x8*)&Ah[ar];
            b_h[i] = *(const bf16x8*)&Bh[br];
            if (SPLIT) { a_l[i] = *(const bf16x8*)&Al[ar]; b_l[i] = *(const bf16x8*)&Bl[br]; }
        }
        #pragma unroll
        for (int mi = 0; mi < 4; mi++)
        #pragma unroll
        for (int ni = 0; ni < 4; ni++) {
            acc[mi][ni] = __builtin_amdgcn_mfma_f32_16x16x32_bf16(a_h[mi], b_h[ni], acc[mi][ni], 0, 0, 0);
            if (SPLIT) {
                acc[mi][ni] = __builtin_amdgcn_mfma_f32_16x16x32_bf16(a_h[mi], b_l[ni], acc[mi][ni], 0, 0, 0);
                acc[mi][ni] = __builtin_amdgcn_mfma_f32_16x16x32_bf16(a_l[mi], b_h[ni], acc[mi][ni], 0, 0, 0);
            }
        }
    }

    // ---- finalize s0/s1 (in-block row dots) ----
    if (ADDS) { s0red[srow][t & 1] = s0part; s1red[srow][t & 1] = s1part; }
    __syncthreads();
    if (ADDS && t < 128) {
        s0arr[t] = s0red[t][0] + s0red[t][1];
        s1arr[t] = s1red[t][0] + s1red[t][1];
    }
    if (ADDS) __syncthreads();

    // ---- apply additive terms; write logits ----
    if (ADDS) {
        float b0 = biasp[0];
        #pragma unroll
        for (int mi = 0; mi < 4; mi++)
        #pragma unroll
        for (int r = 0; r < 4; r++) {
            float s0r = s0arr[wr * 64 + mi * 16 + fg * 4 + r] + b0;
            #pragma unroll
            for (int ni = 0; ni < 4; ni++)
                acc[mi][ni][r] += s0r + s1arr[wc * 64 + ni * 16 + fr];
        }
    }
    #pragma unroll
    for (int mi = 0; mi < 4; mi++)
    #pragma unroll
    for (int r = 0; r < 4; r++) {
        int row = m0 + wr * 64 + mi * 16 + fg * 4 + r;
        #pragma unroll
        for (int ni = 0; ni < 4; ni++)
            Sout[((size_t)b * 1024 + row) * 128 + wc * 64 + ni * 16 + fr] = acc[mi][ni][r];
    }

    // ---- fused stats ----
    bool qmv[4];
    #pragma unroll
    for (int ni = 0; ni < 4; ni++) qmv[ni] = qmsL[wc * 64 + ni * 16 + fr] != 0;
    bool cmb[4][4];
    #pragma unroll
    for (int mi = 0; mi < 4; mi++)
    #pragma unroll
    for (int r = 0; r < 4; r++) cmb[mi][r] = cmsL[wr * 64 + mi * 16 + fg * 4 + r] != 0;

    // R1: row max (reduce over fr within wave, combine wc halves via LDS)
    float rmax[4][4];
    #pragma unroll
    for (int mi = 0; mi < 4; mi++)
    #pragma unroll
    for (int r = 0; r < 4; r++) {
        float m = NEGV;
        #pragma unroll
        for (int ni = 0; ni < 4; ni++) if (qmv[ni]) m = fmaxf(m, acc[mi][ni][r]);
        #pragma unroll
        for (int off = 1; off < 16; off <<= 1) m = fmaxf(m, __shfl_xor(m, off));
        rmax[mi][r] = m;
    }
    if (fr == 0) {
        #pragma unroll
        for (int mi = 0; mi < 4; mi++)
        #pragma unroll
        for (int r = 0; r < 4; r++) red[wc][wr * 64 + mi * 16 + fg * 4 + r] = rmax[mi][r];
    }
    __syncthreads();
    if (t < 128) mrowL[t] = fmaxf(red[0][t], red[1][t]);
    __syncthreads();
    // R2: row exp-sum
    #pragma unroll
    for (int mi = 0; mi < 4; mi++)
    #pragma unroll
    for (int r = 0; r < 4; r++) {
        float mr = mrowL[wr * 64 + mi * 16 + fg * 4 + r];
        float s = 0.f;
        #pragma unroll
        for (int ni = 0; ni < 4; ni++) if (qmv[ni]) s += __expf(acc[mi][ni][r] - mr);
        #pragma unroll
        for (int off = 1; off < 16; off <<= 1) s += __shfl_xor(s, off);
        if (fr == 0) red[wc][wr * 64 + mi * 16 + fg * 4 + r] = s;
    }
    __syncthreads();
    if (t < 128) rowst[(size_t)b * 1024 + m0 + t] = make_float2(mrowL[t], red[0][t] + red[1][t]);
    __syncthreads();
    // C1: column max over this chunk's 128 rows (reduce over fg, combine wr halves)
    float cpart[4];
    #pragma unroll
    for (int ni = 0; ni < 4; ni++) {
        float m = NEGV;
        #pragma unroll
        for (int mi = 0; mi < 4; mi++)
        #pragma unroll
        for (int r = 0; r < 4; r++) if (cmb[mi][r]) m = fmaxf(m, acc[mi][ni][r]);
        m = fmaxf(m, __shfl_xor(m, 16));
        m = fmaxf(m, __shfl_xor(m, 32));
        cpart[ni] = m;
    }
    if (fg == 0) {
        #pragma unroll
        for (int ni = 0; ni < 4; ni++) red[wr][wc * 64 + ni * 16 + fr] = cpart[ni];
    }
    __syncthreads();
    if (t < 128) cmaxL[t] = fmaxf(red[0][t], red[1][t]);
    __syncthreads();
    // C2: column exp-sum
    #pragma unroll
    for (int ni = 0; ni < 4; ni++) {
        float cm = cmaxL[wc * 64 + ni * 16 + fr];
        float s = 0.f;
        #pragma unroll
        for (int mi = 0; mi < 4; mi++)
        #pragma unroll
        for (int r = 0; r < 4; r++) if (cmb[mi][r]) s += __expf(acc[mi][ni][r] - cm);
        s += __shfl_xor(s, 16);
        s += __shfl_xor(s, 32);
        cpart[ni] = s;
    }
    __syncthreads();
    if (fg == 0) {
        #pragma unroll
        for (int ni = 0; ni < 4; ni++) red[wr][wc * 64 + ni * 16 + fr] = cpart[ni];
    }
    __syncthreads();
    if (t < 128) colpart[((size_t)b * 8 + ch) * 128 + t] = make_float2(cmaxL[t], red[0][t] + red[1][t]);
}

// ---------------- emit normalized softmaxes (col-combine inlined) ----------------
__global__ __launch_bounds__(512)
void k_emit(const float* __restrict__ S, const int* __restrict__ qmask,
            const int* __restrict__ cmask, const float2* __restrict__ rowst,
            const float2* __restrict__ colpart, short* __restrict__ Pr,
            short* __restrict__ PcT)
{
    __shared__ float2 colfinL[128];
    const int t = threadIdx.x;
    const int b = (int)(blockIdx.x >> 3), ch = (int)(blockIdx.x & 7);
    const int r0 = ch * 128;
    if (t < 128) {
        float M = NEGV;
        #pragma unroll
        for (int c2 = 0; c2 < 8; c2++) M = fmaxf(M, colpart[((size_t)b * 8 + c2) * 128 + t].x);
        float Ss = 0.f;
        #pragma unroll
        for (int c2 = 0; c2 < 8; c2++) {
            float2 p = colpart[((size_t)b * 8 + c2) * 128 + t];
            Ss += p.y * __expf(p.x - M);
        }
        colfinL[t] = make_float2(M, Ss);
    }
    __syncthreads();
    {   // row softmax, linear layout
        const int q = t & 127, rg = t >> 7;
        const bool qm = qmask[b * 128 + q] != 0;
        #pragma unroll 8
        for (int i = 0; i < 32; i++) {
            int r = r0 + rg * 32 + i;
            size_t idx = ((size_t)b * 1024 + r) * 128 + q;
            float v = S[idx];
            float2 rs = rowst[(size_t)b * 1024 + r];
            float o = qm ? __expf(v - rs.x) / rs.y : 0.f;
            Pr[idx] = f2bf(o);
        }
    }
    {   // column softmax, transposed layout
        const int q2 = t >> 2, ig = t & 3;
        float2 cs = colfinL[q2];
        float inv = 1.f / cs.y;
        short buf[32];
        #pragma unroll
        for (int i = 0; i < 32; i++) {
            int r = r0 + ig * 32 + i;
            bool cm = cmask[b * 1024 + r] != 0;
            float v = S[((size_t)b * 1024 + r) * 128 + q2];
            buf[i] = f2bf(cm ? __expf(v - cs.x) * inv : 0.f);
        }
        short* dst = PcT + ((size_t)b * 128 + q2) * 1024 + r0 + ig * 32;
        #pragma unroll
        for (int j = 0; j < 4; j++) *(bf16x8*)(dst + j * 8) = *(bf16x8*)&buf[j * 8];
    }
}

// ---------------- fused dual K=1024 GEMM: Y{1,2}T[b] = (A{1,2}[b] @ c[b])^T bf16 ----------------
__global__ __launch_bounds__(256)
void k_kgemm2(const short* __restrict__ A1, const short* __restrict__ A2,
              const float* __restrict__ Cc, short* __restrict__ Y1T,
              short* __restrict__ Y2T)
{
    __shared__ short Bs[128 * LDT];
    __shared__ short TT[128 * 136];
    const int t = threadIdx.x;
    const int b = (int)(blockIdx.x >> 2);
    const int n0 = (int)(blockIdx.x & 3) * 128;
    const int lane = t & 63;
    const int wr = (t >> 7) & 1, wc = (t >> 6) & 1;
    const int fr = lane & 15, fg = lane >> 4;
    const int n4 = (t & 31) * 4, kk4 = (t >> 5) * 4;
    f32x4 acc1[4][4] = {}, acc2[4][4] = {};
    for (int k0 = 0; k0 < 1024; k0 += 32) {
        __syncthreads();
        {   // stage c^T tile (fp32 -> bf16)
            const float* bsrc = Cc + ((size_t)b * 1024 + k0 + kk4) * 512 + n0 + n4;
            float4 r0_ = *(const float4*)(bsrc);
            float4 r1_ = *(const float4*)(bsrc + 512);
            float4 r2_ = *(const float4*)(bsrc + 1024);
            float4 r3_ = *(const float4*)(bsrc + 1536);
            const float* p0 = (const float*)&r0_;
            const float* p1 = (const float*)&r1_;
            const float* p2 = (const float*)&r2_;
            const float* p3 = (const float*)&r3_;
            #pragma unroll
            for (int l = 0; l < 4; l++) {
                unsigned d0 = (unsigned)(unsigned short)f2bf(p0[l]) | ((unsigned)(unsigned short)f2bf(p1[l]) << 16);
                unsigned d1 = (unsigned)(unsigned short)f2bf(p2[l]) | ((unsigned)(unsigned short)f2bf(p3[l]) << 16);
                uint2 dd; dd.x = d0; dd.y = d1;
                *(uint2*)&Bs[(n4 + l) * LDT + kk4] = dd;
            }
        }
        __syncthreads();
        bf16x8 a1[4], a2[4], bg[4];
        #pragma unroll
        for (int i = 0; i < 4; i++) {
            size_t arow = (size_t)(b * 128 + wr * 64 + i * 16 + fr) * 1024 + k0 + fg * 8;
            a1[i] = *(const bf16x8*)(A1 + arow);
            a2[i] = *(const bf16x8*)(A2 + arow);
            bg[i] = *(const bf16x8*)&Bs[(wc * 64 + i * 16 + fr) * LDT + fg * 8];
        }
        #pragma unroll
        for (int mi = 0; mi < 4; mi++)
        #pragma unroll
        for (int ni = 0; ni < 4; ni++) {
            acc1[mi][ni] = __builtin_amdgcn_mfma_f32_16x16x32_bf16(a1[mi], bg[ni], acc1[mi][ni], 0, 0, 0);
            acc2[mi][ni] = __builtin_amdgcn_mfma_f32_16x16x32_bf16(a2[mi], bg[ni], acc2[mi][ni], 0, 0, 0);
        }
    }
    // transpose-bounce both outputs through LDS -> coalesced [B,512,128] writes
    const int n = t >> 1, half = t & 1;
    __syncthreads();
    #pragma unroll
    for (int mi = 0; mi < 4; mi++)
    #pragma unroll
    for (int r = 0; r < 4; r++) {
        int ml = wr * 64 + mi * 16 + fg * 4 + r;
        #pragma unroll
        for (int ni = 0; ni < 4; ni++)
            TT[(wc * 64 + ni * 16 + fr) * 136 + ml] = f2bf(acc1[mi][ni][r]);
    }
    __syncthreads();
    {
        short* dst = Y1T + ((size_t)b * 512 + n0 + n) * 128 + half * 64;
        #pragma unroll
        for (int j = 0; j < 8; j++)
            *(bf16x8*)(dst + j * 8) = *(const bf16x8*)&TT[n * 136 + half * 64 + j * 8];
    }
    __syncthreads();
    #pragma unroll
    for (int mi = 0; mi < 4; mi++)
    #pragma unroll
    for (int r = 0; r < 4; r++) {
        int ml = wr * 64 + mi * 16 + fg * 4 + r;
        #pragma unroll
        for (int ni = 0; ni < 4; ni++)
            TT[(wc * 64 + ni * 16 + fr) * 136 + ml] = f2bf(acc2[mi][ni][r]);
    }
    __syncthreads();
    {
        short* dst = Y2T + ((size_t)b * 512 + n0 + n) * 128 + half * 64;
        #pragma unroll
        for (int j = 0; j < 8; j++)
            *(bf16x8*)(dst + j * 8) = *(const bf16x8*)&TT[n * 136 + half * 64 + j * 8];
    }
}

// ---------------- epilogue GEMM (K=128), all operands direct-from-global, no LDS ----------------
template<bool WITHC>
__global__ __launch_bounds__(256)
void k_epi(const short* __restrict__ Pm, const short* __restrict__ BT1,
           const short* __restrict__ BT2, const float* __restrict__ Cc,
           float* __restrict__ out)
{
    const int t = threadIdx.x;
    const int hb = (int)(blockIdx.x & 3);
    const int mb = (int)((blockIdx.x >> 2) & 7);
    const int b  = (int)(blockIdx.x >> 5);
    const int m0 = mb * 128, h0 = hb * 128;
    const int lane = t & 63;
    const int wr = (t >> 7) & 1, wc = (t >> 6) & 1;
    const int fr = lane & 15, fg = lane >> 4;
    f32x4 acc1[4][4] = {}, acc2[4][4] = {};
    const short* Abase  = Pm  + ((size_t)b * 1024 + m0) * 128;
    const short* B1base = BT1 + ((size_t)b * 512 + h0) * 128;
    const short* B2base = BT2 + ((size_t)b * 512 + h0) * 128;
    #pragma unroll
    for (int kk = 0; kk < 4; kk++) {
        const int k0 = kk * 32;
        bf16x8 af[4], b1[4], b2[4];
        #pragma unroll
        for (int i = 0; i < 4; i++) {
            af[i] = *(const bf16x8*)(Abase  + (size_t)(wr * 64 + i * 16 + fr) * 128 + k0 + fg * 8);
            b1[i] = *(const bf16x8*)(B1base + (size_t)(wc * 64 + i * 16 + fr) * 128 + k0 + fg * 8);
            b2[i] = *(const bf16x8*)(B2base + (size_t)(wc * 64 + i * 16 + fr) * 128 + k0 + fg * 8);
        }
        #pragma unroll
        for (int mi = 0; mi < 4; mi++)
        #pragma unroll
        for (int ni = 0; ni < 4; ni++) {
            acc1[mi][ni] = __builtin_amdgcn_mfma_f32_16x16x32_bf16(af[mi], b1[ni], acc1[mi][ni], 0, 0, 0);
            acc2[mi][ni] = __builtin_amdgcn_mfma_f32_16x16x32_bf16(af[mi], b2[ni], acc2[mi][ni], 0, 0, 0);
        }
    }
    const size_t crow_base = (size_t)b * 1024 + m0;
    #pragma unroll
    for (int mi = 0; mi < 4; mi++)
    #pragma unroll
    for (int r = 0; r < 4; r++) {
        int rowl = wr * 64 + mi * 16 + fg * 4 + r;
        size_t obase = (crow_base + rowl) * 3072 + h0;
        #pragma unroll
        for (int ni = 0; ni < 4; ni++) {
            int col = wc * 64 + ni * 16 + fr;
            float av = acc1[mi][ni][r], bv2 = acc2[mi][ni][r];
            if (WITHC) {
                float cv = Cc[(crow_base + rowl) * 512 + h0 + col];
                out[obase + col]        = cv;
                out[obase + col + 512]  = av;
                out[obase + col + 1024] = cv * av;
                out[obase + col + 1536] = cv * bv2;
            } else {
                out[obase + col + 2048] = bv2;
                out[obase + col + 2560] = av;
            }
        }
    }
}

// ---------------- host launcher ----------------
extern "C" void kernel_launch(void* const* d_in, const int* in_sizes, int n_in,
                              void* d_out, int out_size, void* d_ws, size_t ws_size,
                              hipStream_t stream)
{
    const float* c     = (const float*)d_in[0];
    const float* q     = (const float*)d_in[1];
    const int*   cmask = (const int*)d_in[2];
    const int*   qmask = (const int*)d_in[3];
    const float* cwv   = (const float*)d_in[4];
    const float* qwv   = (const float*)d_in[5];
    const float* cqw   = (const float*)d_in[6];
    const float* bias  = (const float*)d_in[7];
    const float* W1    = (const float*)d_in[8];
    const float* b1    = (const float*)d_in[9];
    const float* W2    = (const float*)d_in[10];
    const float* b2    = (const float*)d_in[11];
    float* out = (float*)d_out;

    char* ws = (char*)d_ws;
    size_t off = 0;
    auto alloc = [&](size_t bytes) -> char* {
        char* p = ws + off;
        off = (off + bytes + 255) & ~(size_t)255;
        return p;
    };
    short* w1th = (short*)alloc(512 * 512 * 2);
    short* w1tl = (short*)alloc(512 * 512 * 2);
    short* w2th = (short*)alloc(512 * 512 * 2);
    short* w2tl = (short*)alloc(512 * 512 * 2);
    float* z1   = (float*)alloc((size_t)8192 * 512 * 4);     // layer-1 act; reused for binT/bcoT
    float* qp   = (float*)alloc((size_t)8192 * 512 * 4);
    short* qT   = (short*)alloc((size_t)64 * 512 * 128 * 2);
    short* qpT  = (short*)alloc((size_t)64 * 512 * 128 * 2);
    float* simb = (float*)alloc((size_t)64 * 1024 * 128 * 4);
    float2* rowst   = (float2*)alloc((size_t)64 * 1024 * 8);
    float2* colpart = (float2*)alloc((size_t)64 * 8 * 128 * 8);
    short* s1s  = (short*)alloc((size_t)64 * 1024 * 128 * 2);
    short* s2sT = (short*)alloc((size_t)64 * 128 * 1024 * 2);
    short* sc1  = (short*)alloc((size_t)64 * 1024 * 128 * 2);
    short* sc2T = (short*)alloc((size_t)64 * 128 * 1024 * 2);
    short* binT = (short*)z1;                                 // [B,512,128] bf16
    short* bcoT = ((short*)z1) + (size_t)64 * 512 * 128;

    k_prep_w<<<2048, 256, 0, stream>>>(W1, W2, w1th, w1tl, w2th, w2tl);
    k_linear<false><<<256, 256, 0, stream>>>(q, w1th, w1tl, b1, z1, nullptr);
    k_linear<true><<<256, 256, 0, stream>>>(z1, w2th, w2tl, b2, qp, qpT);
    k_transq<<<256, 256, 0, stream>>>(q, qT);

    // sim pipeline (stats fused into the GEMM)
    k_att_gemm<false, true, true><<<512, 256, 0, stream>>>(
        c, q, cqw, cwv, qwv, bias, qmask, cmask, simb, rowst, colpart);
    k_emit<<<512, 512, 0, stream>>>(simb, qmask, cmask, rowst, colpart, s1s, s2sT);

    // scoat pipeline (split precision)
    k_att_gemm<true, false, false><<<512, 256, 0, stream>>>(
        c, qp, nullptr, nullptr, nullptr, nullptr, qmask, cmask, simb, rowst, colpart);
    k_emit<<<512, 512, 0, stream>>>(simb, qmask, cmask, rowst, colpart, sc1, sc2T);

    // fused dual K=1024 GEMM (c staged once), transposed bf16 outputs
    k_kgemm2<<<256, 256, 0, stream>>>(s2sT, sc2T, c, binT, bcoT);

    // fused output epilogues (no-LDS direct-fragment GEMMs)
    k_epi<true><<<2048, 256, 0, stream>>>(s1s, qT, binT, c, out);
    k_epi<false><<<2048, 256, 0, stream>>>(sc1, qpT, bcoT, nullptr, out);
}